// Round 1
// baseline (1823.994 us; speedup 1.0000x reference)
//
#include <hip/hip_runtime.h>

// ---------------------------------------------------------------------------
// miniGPT forward: 4 layers, D=768, H=12, HID=3072, V=32000, B=4, S=1024
// bf16 MFMA GEMMs (fp32 accum), fp32 LN/softmax/residual stream.
// ---------------------------------------------------------------------------

typedef __bf16 bf16_t;
typedef bf16_t bf16x8 __attribute__((ext_vector_type(8)));
typedef float f32x4 __attribute__((ext_vector_type(4)));

#define GLD16(G, L) __builtin_amdgcn_global_load_lds(                          \
    (const __attribute__((address_space(1))) unsigned int*)(const void*)(G),   \
    (__attribute__((address_space(3))) unsigned int*)(void*)(L), 16, 0, 0)

__device__ __forceinline__ f32x4 mfma16(bf16x8 a, bf16x8 b, f32x4 c) {
  return __builtin_amdgcn_mfma_f32_16x16x32_bf16(a, b, c, 0, 0, 0);
}

#define RED16_MAX(x) { x = fmaxf(x, __shfl_xor(x, 1)); x = fmaxf(x, __shfl_xor(x, 2)); \
                       x = fmaxf(x, __shfl_xor(x, 4)); x = fmaxf(x, __shfl_xor(x, 8)); }
#define RED16_SUM(x) { x += __shfl_xor(x, 1); x += __shfl_xor(x, 2); \
                       x += __shfl_xor(x, 4); x += __shfl_xor(x, 8); }

// ---------------- transpose + f32->bf16 convert: in[K][N] -> out[N][K] ------
__global__ __launch_bounds__(256)
void tconv_k(const float* __restrict__ in, bf16_t* __restrict__ out, int K, int N) {
  __shared__ float tile[32][33];
  const int n0 = blockIdx.x * 32, k0 = blockIdx.y * 32;
  const int tx = threadIdx.x & 31, ty = threadIdx.x >> 5;  // ty 0..7
#pragma unroll
  for (int j = 0; j < 4; ++j)
    tile[ty + j * 8][tx] = in[(size_t)(k0 + ty + j * 8) * N + n0 + tx];
  __syncthreads();
#pragma unroll
  for (int j = 0; j < 4; ++j)
    out[(size_t)(n0 + ty + j * 8) * K + k0 + tx] = (bf16_t)tile[tx][ty + j * 8];
}

// ---------------- concat q/k/v biases per layer -> [L][2304] ----------------
__global__ void qkvbias_k(const float* __restrict__ bq, const float* __restrict__ bk,
                          const float* __restrict__ bv, float* __restrict__ out) {
  const int l = blockIdx.x;
  for (int j = threadIdx.x; j < 2304; j += 256) {
    float v = (j < 768) ? bq[l * 768 + j]
            : (j < 1536) ? bk[l * 768 + j - 768]
                         : bv[l * 768 + j - 1536];
    out[l * 2304 + j] = v;
  }
}

// ---------------- embedding + positional encoding ---------------------------
__global__ __launch_bounds__(256)
void embed_k(const int* __restrict__ tok, const float* __restrict__ emb,
             const float* __restrict__ pe, float* __restrict__ xf) {
  const int row = blockIdx.x, tid = threadIdx.x;
  const int s = row & 1023;
  const int t = tok[row];
  float* o = xf + (size_t)row * 768;
  const float* e = emb + (size_t)t * 768;
  const float* p = pe + (size_t)s * 768;
  o[tid]       = e[tid]       + p[tid];
  o[tid + 256] = e[tid + 256] + p[tid + 256];
  o[tid + 512] = e[tid + 512] + p[tid + 512];
}

// ---------------- layernorm (fp32 in, bf16 out), one block per row ----------
__global__ __launch_bounds__(256)
void ln_k(const float* __restrict__ x, const float* __restrict__ g,
          const float* __restrict__ bb, bf16_t* __restrict__ out) {
  const int row = blockIdx.x, tid = threadIdx.x;
  const int wave = tid >> 6, lane = tid & 63;
  const float* xr = x + (size_t)row * 768;
  float v0 = xr[tid], v1 = xr[tid + 256], v2 = xr[tid + 512];
  float s = v0 + v1 + v2;
  __shared__ float red[4];
#pragma unroll
  for (int off = 32; off; off >>= 1) s += __shfl_xor(s, off);
  if (lane == 0) red[wave] = s;
  __syncthreads();
  const float mu = (red[0] + red[1] + red[2] + red[3]) * (1.0f / 768.0f);
  const float d0 = v0 - mu, d1 = v1 - mu, d2 = v2 - mu;
  float s2 = d0 * d0 + d1 * d1 + d2 * d2;
#pragma unroll
  for (int off = 32; off; off >>= 1) s2 += __shfl_xor(s2, off);
  __syncthreads();
  if (lane == 0) red[wave] = s2;
  __syncthreads();
  const float rstd = rsqrtf((red[0] + red[1] + red[2] + red[3]) * (1.0f / 768.0f) + 1e-5f);
  bf16_t* orow = out + (size_t)row * 768;
  orow[tid]       = (bf16_t)(d0 * rstd * g[tid]       + bb[tid]);
  orow[tid + 256] = (bf16_t)(d1 * rstd * g[tid + 256] + bb[tid + 256]);
  orow[tid + 512] = (bf16_t)(d2 * rstd * g[tid + 512] + bb[tid + 512]);
}

// ---------------- GEMM: C[M,N] = A[M,K](bf16) * BT[N,K](bf16)^T + epilogue --
// 128x128 tile, BK=64, 4 waves, each wave owns 64x64 (4x4 frags of 16x16x32).
template <bool BIAS, bool RELU, bool RESID, bool OUTF32>
__global__ __launch_bounds__(256)
void gemm_bt(const bf16_t* __restrict__ A, const bf16_t* __restrict__ BT,
             const float* __restrict__ bias, const float* __restrict__ resid,
             float* __restrict__ outF, bf16_t* __restrict__ outB,
             int M, int N, int K) {
  __shared__ __align__(16) bf16_t As[128 * 64];
  __shared__ __align__(16) bf16_t Bs[128 * 64];
  const int tiles_n = N >> 7;
  const int tm = blockIdx.x / tiles_n, tn = blockIdx.x % tiles_n;
  const int tid = threadIdx.x;
  const int wave = tid >> 6, lane = tid & 63;
  const int wr = wave >> 1, wc = wave & 1;
  const int lrow = lane & 15, koct = lane >> 4;
  const bf16_t* Ab = A + (size_t)tm * 128 * K;
  const bf16_t* Bb = BT + (size_t)tn * 128 * K;
  const int srow = tid >> 3, scol = (tid & 7) << 3;

  f32x4 acc[4][4] = {};

  for (int k0 = 0; k0 < K; k0 += 64) {
    __syncthreads();
#pragma unroll
    for (int i = 0; i < 4; ++i) {
      GLD16(Ab + (size_t)(i * 32 + srow) * K + k0 + scol, As + i * 2048 + tid * 8);
      GLD16(Bb + (size_t)(i * 32 + srow) * K + k0 + scol, Bs + i * 2048 + tid * 8);
    }
    __syncthreads();
#pragma unroll
    for (int kk = 0; kk < 2; ++kk) {
      bf16x8 af[4], bfr[4];
#pragma unroll
      for (int mi = 0; mi < 4; ++mi)
        af[mi] = *(const bf16x8*)&As[(wr * 64 + mi * 16 + lrow) * 64 + kk * 32 + koct * 8];
#pragma unroll
      for (int ni = 0; ni < 4; ++ni)
        bfr[ni] = *(const bf16x8*)&Bs[(wc * 64 + ni * 16 + lrow) * 64 + kk * 32 + koct * 8];
#pragma unroll
      for (int mi = 0; mi < 4; ++mi)
#pragma unroll
        for (int ni = 0; ni < 4; ++ni)
          acc[mi][ni] = mfma16(af[mi], bfr[ni], acc[mi][ni]);
    }
  }

  const int row0 = tm * 128 + wr * 64, col0 = tn * 128 + wc * 64;
#pragma unroll
  for (int ni = 0; ni < 4; ++ni) {
    const int col = col0 + ni * 16 + lrow;
    const float bv = BIAS ? bias[col] : 0.0f;
#pragma unroll
    for (int mi = 0; mi < 4; ++mi) {
#pragma unroll
      for (int r = 0; r < 4; ++r) {
        const int row = row0 + mi * 16 + koct * 4 + r;
        float v = acc[mi][ni][r] + bv;
        if (RELU) v = fmaxf(v, 0.0f);
        const size_t idx = (size_t)row * N + col;
        if (RESID) v += resid[idx];
        if (OUTF32) outF[idx] = v;
        else        outB[idx] = (bf16_t)v;
      }
    }
  }
}

// ---------------- fused causal attention (flash-style) ----------------------
// qkv: [4096][2304] bf16 rows (q|k|v per head h at h*64 / 768+h*64 / 1536+h*64)
// ab : [4096][768] bf16. Grid: (S/64, H, B), 256 threads (4 waves x 16 q-rows).
__global__ __launch_bounds__(256)
void attn_k(const bf16_t* __restrict__ qkv, bf16_t* __restrict__ ab) {
  __shared__ __align__(16) bf16_t Qs[64 * 64];
  __shared__ __align__(16) bf16_t Ks[64 * 64];
  __shared__ __align__(16) bf16_t Vt[64 * 64];
  __shared__ __align__(16) bf16_t Ps[4][16 * 64];
  const int qt = blockIdx.x, h = blockIdx.y, b = blockIdx.z;
  const int tid = threadIdx.x;
  const int wave = tid >> 6, lane = tid & 63;
  const int lrow = lane & 15, koct = lane >> 4;
  const float scale = 0.03608439182435161f;  // 1/sqrt(768)  (module scales by d_model)

  const size_t RS = 2304;
  const bf16_t* qbase = qkv + h * 64;
  const bf16_t* kbase = qkv + 768 + h * 64;
  const bf16_t* vbase = qkv + 1536 + h * 64;

  {  // stage Q tile [64 rows][64 dims]
    const int r = tid >> 3, c = (tid & 7) << 3;
#pragma unroll
    for (int i = 0; i < 2; ++i)
      GLD16(qbase + (size_t)(b * 1024 + qt * 64 + i * 32 + r) * RS + c,
            Qs + i * 2048 + tid * 8);
  }
  __syncthreads();
  bf16x8 qf[2];
  qf[0] = *(const bf16x8*)&Qs[(wave * 16 + lrow) * 64 + koct * 8];
  qf[1] = *(const bf16x8*)&Qs[(wave * 16 + lrow) * 64 + 32 + koct * 8];

  float m_r[4], l_r[4];
  f32x4 o[4] = {};
#pragma unroll
  for (int r = 0; r < 4; ++r) { m_r[r] = -1e30f; l_r[r] = 0.0f; }

  for (int kt = 0; kt <= qt; ++kt) {
    __syncthreads();  // protect K/V/P LDS reuse from previous iteration
    {
      const int r = tid >> 3, c = (tid & 7) << 3;
#pragma unroll
      for (int i = 0; i < 2; ++i)
        GLD16(kbase + (size_t)(b * 1024 + kt * 64 + i * 32 + r) * RS + c,
              Ks + i * 2048 + tid * 8);
    }
    for (int i = tid; i < 4096; i += 256) {  // V transposed: Vt[dim][kcol]
      const int r = i >> 6, c = i & 63;
      Vt[c * 64 + r] = vbase[(size_t)(b * 1024 + kt * 64 + r) * RS + c];
    }
    __syncthreads();

    // S = Q K^T  (per wave: 16 q-rows x 64 k-cols)
    f32x4 s[4] = {};
#pragma unroll
    for (int ni = 0; ni < 4; ++ni) {
      bf16x8 kf0 = *(const bf16x8*)&Ks[(ni * 16 + lrow) * 64 + koct * 8];
      bf16x8 kf1 = *(const bf16x8*)&Ks[(ni * 16 + lrow) * 64 + 32 + koct * 8];
      s[ni] = mfma16(qf[0], kf0, s[ni]);
      s[ni] = mfma16(qf[1], kf1, s[ni]);
    }

    // scale + causal mask + online softmax update
    const int qrow = qt * 64 + wave * 16 + koct * 4;  // + r
    float rm[4];
#pragma unroll
    for (int r = 0; r < 4; ++r) rm[r] = -1e30f;
#pragma unroll
    for (int ni = 0; ni < 4; ++ni) {
      const int kcol = kt * 64 + ni * 16 + lrow;
#pragma unroll
      for (int r = 0; r < 4; ++r) {
        float v = s[ni][r] * scale;
        if (kcol > qrow + r) v = -1e30f;
        s[ni][r] = v;
        rm[r] = fmaxf(rm[r], v);
      }
    }
#pragma unroll
    for (int r = 0; r < 4; ++r) RED16_MAX(rm[r]);
    float corr[4], ps[4];
#pragma unroll
    for (int r = 0; r < 4; ++r) {
      const float mn = fmaxf(m_r[r], rm[r]);
      corr[r] = __expf(m_r[r] - mn);
      m_r[r] = mn;
      ps[r] = 0.0f;
    }
#pragma unroll
    for (int ni = 0; ni < 4; ++ni)
#pragma unroll
      for (int r = 0; r < 4; ++r) {
        const float p = __expf(s[ni][r] - m_r[r]);
        s[ni][r] = p;
        ps[r] += p;
      }
#pragma unroll
    for (int r = 0; r < 4; ++r) RED16_SUM(ps[r]);
#pragma unroll
    for (int r = 0; r < 4; ++r) l_r[r] = l_r[r] * corr[r] + ps[r];
#pragma unroll
    for (int ni = 0; ni < 4; ++ni)
#pragma unroll
      for (int r = 0; r < 4; ++r) o[ni][r] *= corr[r];

    // P (C-layout) -> LDS (A-layout source) as bf16
#pragma unroll
    for (int ni = 0; ni < 4; ++ni)
#pragma unroll
      for (int r = 0; r < 4; ++r)
        Ps[wave][(koct * 4 + r) * 64 + ni * 16 + lrow] = (bf16_t)s[ni][r];
    __syncthreads();

    // O += P V
    bf16x8 pa0 = *(const bf16x8*)&Ps[wave][lrow * 64 + koct * 8];
    bf16x8 pa1 = *(const bf16x8*)&Ps[wave][lrow * 64 + 32 + koct * 8];
#pragma unroll
    for (int ni = 0; ni < 4; ++ni) {
      bf16x8 vf0 = *(const bf16x8*)&Vt[(ni * 16 + lrow) * 64 + koct * 8];
      bf16x8 vf1 = *(const bf16x8*)&Vt[(ni * 16 + lrow) * 64 + 32 + koct * 8];
      o[ni] = mfma16(pa0, vf0, o[ni]);
      o[ni] = mfma16(pa1, vf1, o[ni]);
    }
  }

  // epilogue: O /= l, write [B,S,H*HD]
#pragma unroll
  for (int r = 0; r < 4; ++r) {
    const float inv = 1.0f / l_r[r];
    const int row = qt * 64 + wave * 16 + koct * 4 + r;
#pragma unroll
    for (int ni = 0; ni < 4; ++ni)
      ab[(size_t)(b * 1024 + row) * 768 + h * 64 + ni * 16 + lrow] =
          (bf16_t)(o[ni][r] * inv);
  }
}

// ---------------------------------------------------------------------------
extern "C" void kernel_launch(void* const* d_in, const int* in_sizes, int n_in,
                              void* d_out, int out_size, void* d_ws, size_t ws_size,
                              hipStream_t stream) {
  (void)in_sizes; (void)n_in; (void)out_size; (void)ws_size;
  const int*   tok   = (const int*)d_in[0];
  const float* emb   = (const float*)d_in[1];
  const float* pe    = (const float*)d_in[2];
  const float* ln1_g = (const float*)d_in[3];
  const float* ln1_b = (const float*)d_in[4];
  const float* wq    = (const float*)d_in[5];
  const float* bq    = (const float*)d_in[6];
  const float* wk    = (const float*)d_in[7];
  const float* bk    = (const float*)d_in[8];
  const float* wv    = (const float*)d_in[9];
  const float* bv    = (const float*)d_in[10];
  const float* wo    = (const float*)d_in[11];
  const float* bo    = (const float*)d_in[12];
  const float* ln2_g = (const float*)d_in[13];
  const float* ln2_b = (const float*)d_in[14];
  const float* w1    = (const float*)d_in[15];
  const float* b1    = (const float*)d_in[16];
  const float* w2    = (const float*)d_in[17];
  const float* b2    = (const float*)d_in[18];
  const float* lnf_g = (const float*)d_in[19];
  const float* lnf_b = (const float*)d_in[20];
  const float* w_out = (const float*)d_in[21];
  float* out = (float*)d_out;

  char* ws = (char*)d_ws;
  size_t off = 0;
  auto alloc = [&](size_t bytes) -> void* {
    void* p = ws + off;
    off += (bytes + 255) & ~(size_t)255;
    return p;
  };
  float*  xf      = (float*)alloc(4096ull * 768 * 4);
  bf16_t* hb      = (bf16_t*)alloc(4096ull * 768 * 2);
  bf16_t* qkvb    = (bf16_t*)alloc(4096ull * 2304 * 2);
  bf16_t* ab      = (bf16_t*)alloc(4096ull * 768 * 2);
  bf16_t* fb      = (bf16_t*)alloc(4096ull * 3072 * 2);
  float*  qkvbias = (float*)alloc(4ull * 2304 * 4);
  bf16_t* wqkvT   = (bf16_t*)alloc(4ull * 2304 * 768 * 2);
  bf16_t* woT     = (bf16_t*)alloc(4ull * 768 * 768 * 2);
  bf16_t* w1T     = (bf16_t*)alloc(4ull * 3072 * 768 * 2);
  bf16_t* w2T     = (bf16_t*)alloc(4ull * 768 * 3072 * 2);
  bf16_t* woutT   = (bf16_t*)alloc(32000ull * 768 * 2);

  // ---- weight convert+transpose (per call; kernel must be stateless) ----
  for (int l = 0; l < 4; ++l) {
    tconv_k<<<dim3(24, 24), 256, 0, stream>>>(wq + (size_t)l * 768 * 768,
        wqkvT + (size_t)l * 2304 * 768, 768, 768);
    tconv_k<<<dim3(24, 24), 256, 0, stream>>>(wk + (size_t)l * 768 * 768,
        wqkvT + (size_t)l * 2304 * 768 + 768 * 768, 768, 768);
    tconv_k<<<dim3(24, 24), 256, 0, stream>>>(wv + (size_t)l * 768 * 768,
        wqkvT + (size_t)l * 2304 * 768 + 2 * 768 * 768, 768, 768);
    tconv_k<<<dim3(24, 24), 256, 0, stream>>>(wo + (size_t)l * 768 * 768,
        woT + (size_t)l * 768 * 768, 768, 768);
    tconv_k<<<dim3(96, 24), 256, 0, stream>>>(w1 + (size_t)l * 768 * 3072,
        w1T + (size_t)l * 3072 * 768, 768, 3072);
    tconv_k<<<dim3(24, 96), 256, 0, stream>>>(w2 + (size_t)l * 3072 * 768,
        w2T + (size_t)l * 768 * 3072, 3072, 768);
  }
  tconv_k<<<dim3(1000, 24), 256, 0, stream>>>(w_out, woutT, 768, 32000);
  qkvbias_k<<<4, 256, 0, stream>>>(bq, bk, bv, qkvbias);

  // ---- forward ----
  embed_k<<<4096, 256, 0, stream>>>(tok, emb, pe, xf);

  for (int l = 0; l < 4; ++l) {
    ln_k<<<4096, 256, 0, stream>>>(xf, ln1_g + l * 768, ln1_b + l * 768, hb);
    gemm_bt<true, false, false, false><<<32 * 18, 256, 0, stream>>>(
        hb, wqkvT + (size_t)l * 2304 * 768, qkvbias + l * 2304,
        nullptr, nullptr, qkvb, 4096, 2304, 768);
    attn_k<<<dim3(16, 12, 4), 256, 0, stream>>>(qkvb, ab);
    gemm_bt<true, false, true, true><<<32 * 6, 256, 0, stream>>>(
        ab, woT + (size_t)l * 768 * 768, bo + l * 768,
        xf, xf, nullptr, 4096, 768, 768);
    ln_k<<<4096, 256, 0, stream>>>(xf, ln2_g + l * 768, ln2_b + l * 768, hb);
    gemm_bt<true, true, false, false><<<32 * 24, 256, 0, stream>>>(
        hb, w1T + (size_t)l * 3072 * 768, b1 + l * 3072,
        nullptr, nullptr, fb, 4096, 3072, 768);
    gemm_bt<true, false, true, true><<<32 * 6, 256, 0, stream>>>(
        fb, w2T + (size_t)l * 768 * 3072, b2 + l * 768,
        xf, xf, nullptr, 4096, 768, 3072);
  }
  ln_k<<<4096, 256, 0, stream>>>(xf, lnf_g, lnf_b, hb);
  gemm_bt<false, false, false, true><<<32 * 250, 256, 0, stream>>>(
      hb, woutT, nullptr, nullptr, out, nullptr, 4096, 32000, 768);
}